// Round 4
// baseline (117.216 us; speedup 1.0000x reference)
//
#include <hip/hip_runtime.h>
#include <math.h>

#define NB 8
#define NP 512
#define NF 512
#define NH 64
#define NW 64
#define FEXPAND 0.02f
#define FEPS 1e-10f

#define IMG_OFF 0
#define PROB_OFF (NB*NH*NW*3)            /* 98304  */
#define NRM_OFF  (PROB_OFF + NB*NH*NW)   /* 131072 */
#define MASK_OFF (NRM_OFF + NB*NF*3)     /* 143360 */

// Barycentric weights, bit-exact vs NumPy f32 elementwise evaluation:
// w0 = ((by-cy)*(x-cx) + (cx-bx)*(y-cy)) / det_safe, etc.
// No FMA contraction (sign of these decides coverage -> discrete output flips).
__device__ __forceinline__ void bary(float e0x, float e0y, float e1x, float e1y,
                                     float det_safe, float cx, float cy,
                                     float x, float y,
                                     float& w0, float& w1, float& w2,
                                     float& dxc, float& dyc) {
  dxc = x - cx; dyc = y - cy;
  float n0 = __fadd_rn(__fmul_rn(e0x, dxc), __fmul_rn(e0y, dyc));
  float n1 = __fadd_rn(__fmul_rn(e1x, dxc), __fmul_rn(e1y, dyc));
  w0 = __fdiv_rn(n0, det_safe);
  w1 = __fdiv_rn(n1, det_safe);
  w2 = __fsub_rn(__fsub_rn(1.0f, w0), w1);
}

// Normal kernel, f32 with FMA-CONTRACTED cross product (XLA pattern):
//   n_i = fmaf(a1, b2, -fl(a2*b1))
// Evidence: plain-f32 (r1) and exact-f64 (r3) both miss by O(1) on the same
// elements; f64 invariance r2->r3 pins the failures on exact-degenerate faces
// (repeated vertex index) where elementwise cross == 0 exactly but the FMA
// form yields the product's rounding residual (~1e-8 >> 1e-12 eps), which the
// golden then NORMALIZES into a unit noise vector. Only bit-replication of
// the contraction reproduces those.
__global__ __launch_bounds__(256) void normals_out(
    const float* __restrict__ verts, const int* __restrict__ faces,
    const float* __restrict__ rot, const float* __restrict__ pos,
    float* __restrict__ nrm)
{
  int t = blockIdx.x * 256 + threadIdx.x;
  if (t >= NB * NF) return;
  int b = t >> 9;
  int i0 = faces[t*3+0], i1 = faces[t*3+1], i2 = faces[t*3+2];
  const float* vb = verts + (size_t)b * NP * 3;
  float R0=rot[b*9+0],R1=rot[b*9+1],R2=rot[b*9+2];
  float R3=rot[b*9+3],R4=rot[b*9+4],R5=rot[b*9+5];
  float R6=rot[b*9+6],R7=rot[b*9+7],R8=rot[b*9+8];
  float px = pos[b*3+0], py = pos[b*3+1], pz = pos[b*3+2];

  const float* va = vb + (size_t)i0*3;
  float d0x=__fsub_rn(va[0],px), d0y=__fsub_rn(va[1],py), d0z=__fsub_rn(va[2],pz);
  float ax_ = __fadd_rn(__fadd_rn(__fmul_rn(R0,d0x),__fmul_rn(R1,d0y)),__fmul_rn(R2,d0z));
  float ay_ = __fadd_rn(__fadd_rn(__fmul_rn(R3,d0x),__fmul_rn(R4,d0y)),__fmul_rn(R5,d0z));
  float az_ = __fadd_rn(__fadd_rn(__fmul_rn(R6,d0x),__fmul_rn(R7,d0y)),__fmul_rn(R8,d0z));
  const float* vbp = vb + (size_t)i1*3;
  float d1x=__fsub_rn(vbp[0],px), d1y=__fsub_rn(vbp[1],py), d1z=__fsub_rn(vbp[2],pz);
  float bx_ = __fadd_rn(__fadd_rn(__fmul_rn(R0,d1x),__fmul_rn(R1,d1y)),__fmul_rn(R2,d1z));
  float by_ = __fadd_rn(__fadd_rn(__fmul_rn(R3,d1x),__fmul_rn(R4,d1y)),__fmul_rn(R5,d1z));
  float bz_ = __fadd_rn(__fadd_rn(__fmul_rn(R6,d1x),__fmul_rn(R7,d1y)),__fmul_rn(R8,d1z));
  const float* vc = vb + (size_t)i2*3;
  float d2x=__fsub_rn(vc[0],px), d2y=__fsub_rn(vc[1],py), d2z=__fsub_rn(vc[2],pz);
  float cx_ = __fadd_rn(__fadd_rn(__fmul_rn(R0,d2x),__fmul_rn(R1,d2y)),__fmul_rn(R2,d2z));
  float cy_ = __fadd_rn(__fadd_rn(__fmul_rn(R3,d2x),__fmul_rn(R4,d2y)),__fmul_rn(R5,d2z));
  float cz_ = __fadd_rn(__fadd_rn(__fmul_rn(R6,d2x),__fmul_rn(R7,d2y)),__fmul_rn(R8,d2z));

  float e1x=__fsub_rn(bx_,ax_), e1y=__fsub_rn(by_,ay_), e1z=__fsub_rn(bz_,az_);
  float e2x=__fsub_rn(cx_,ax_), e2y=__fsub_rn(cy_,ay_), e2z=__fsub_rn(cz_,az_);

  // cross with FMA contraction: n = fma(a1, b2, -(a2*b1))
  float m0 = __fmul_rn(e1z, e2y);
  float nx = __fmaf_rn(e1y, e2z, -m0);
  float m1 = __fmul_rn(e1x, e2z);
  float ny = __fmaf_rn(e1z, e2x, -m1);
  float m2 = __fmul_rn(e1y, e2x);
  float nz = __fmaf_rn(e1x, e2y, -m2);

  float nn = __fsqrt_rn(__fadd_rn(__fadd_rn(__fmul_rn(nx,nx),__fmul_rn(ny,ny)),
                                  __fmul_rn(nz,nz)));
  float den = __fadd_rn(nn, 1e-12f);
  nrm[t*3+0] = __fdiv_rn(nx, den);
  nrm[t*3+1] = __fdiv_rn(ny, den);
  nrm[t*3+2] = __fdiv_rn(nz, den);
}

// Per-face setup feeding the raster: 12-float record to ws:
// [ax,ay,bx,by, cx,cy,det_safe,za, zb,zc,valid,pad]  (byte-identical to the
// version whose imrender/improb PASS — do not touch)
__global__ __launch_bounds__(256) void face_setup(
    const float* __restrict__ verts, const int* __restrict__ faces,
    const float* __restrict__ rot, const float* __restrict__ pos,
    const float* __restrict__ proj, float* __restrict__ fd)
{
  int t = blockIdx.x * 256 + threadIdx.x;
  if (t >= NB * NF) return;
  int b = t >> 9;  // NF == 512
  float p0 = proj[0], p1 = proj[1], p2 = proj[2];
  float R0=rot[b*9+0],R1=rot[b*9+1],R2=rot[b*9+2];
  float R3=rot[b*9+3],R4=rot[b*9+4],R5=rot[b*9+5];
  float R6=rot[b*9+6],R7=rot[b*9+7],R8=rot[b*9+8];
  float ppx=pos[b*3+0], ppy=pos[b*3+1], ppz=pos[b*3+2];
  int idxs[3] = { faces[t*3+0], faces[t*3+1], faces[t*3+2] };
  float X[3],Y[3],Z[3],SX[3],SY[3];
#pragma unroll
  for (int k = 0; k < 3; ++k) {
    const float* v = verts + ((size_t)b*NP + idxs[k])*3;
    float dx = v[0]-ppx, dy = v[1]-ppy, dz = v[2]-ppz;
    // pcam_i = sum_j R[i][j]*(v-pos)_j, left-to-right, no FMA
    float pcx = __fadd_rn(__fadd_rn(__fmul_rn(R0,dx),__fmul_rn(R1,dy)),__fmul_rn(R2,dz));
    float pcy = __fadd_rn(__fadd_rn(__fmul_rn(R3,dx),__fmul_rn(R4,dy)),__fmul_rn(R5,dz));
    float pcz = __fadd_rn(__fadd_rn(__fmul_rn(R6,dx),__fmul_rn(R7,dy)),__fmul_rn(R8,dz));
    X[k]=pcx; Y[k]=pcy; Z[k]=pcz;
    float dn = __fmul_rn(pcz, p2);
    SX[k] = __fdiv_rn(__fmul_rn(pcx, p0), dn);
    SY[k] = __fdiv_rn(__fmul_rn(pcy, p1), dn);
  }
  // normal.z sign gates 'valid' -> keep exact f32 (matches ref normalz)
  float e1x=X[1]-X[0], e1y=Y[1]-Y[0];
  float e2x=X[2]-X[0], e2y=Y[2]-Y[0];
  float nz = __fsub_rn(__fmul_rn(e1x,e2y), __fmul_rn(e1y,e2x));

  float ax=SX[0],ay=SY[0],bx=SX[1],by=SY[1],cx=SX[2],cy=SY[2];
  float det = __fadd_rn(__fmul_rn(__fsub_rn(by,cy),__fsub_rn(ax,cx)),
                        __fmul_rn(__fsub_rn(cx,bx),__fsub_rn(ay,cy)));
  float det_safe = (fabsf(det) < FEPS) ? FEPS : det;
  float validf = ((nz > 0.0f) && (fabsf(det) > FEPS)) ? 1.0f : 0.0f;
  float* o = fd + (size_t)t*12;
  o[0]=ax; o[1]=ay; o[2]=bx; o[3]=by; o[4]=cx; o[5]=cy;
  o[6]=det_safe; o[7]=Z[0]; o[8]=Z[1]; o[9]=Z[2]; o[10]=validf; o[11]=0.0f;
}

#define CHUNK 128
// LDS per face (36 floats, 144B -> float4-aligned, fg stride breaks bank aliasing):
//  [0..3]  e0x,e0y,e1x,e1y   [4..7]  cx,cy,det_safe,valid
//  [8..11] za,zb,zc,pad      [12..15] xmin,xmax,ymin,ymax
//  [16..19] ax,ay,bx,by      [20..23] vABx,vABy,invLAB,pad
//  [24..27] vBCx,vBCy,invLBC,pad   [28..31] vCAx,vCAy,invLCA,pad  [32..35] pad
__global__ __launch_bounds__(256) void raster(
    const float* __restrict__ fd, const int* __restrict__ faces,
    const float* __restrict__ colors, float* __restrict__ out)
{
  __shared__ __align__(16) float sf[CHUNK][36];
  int tid  = threadIdx.x;
  int wave = tid >> 6;
  int lane = tid & 63;
  int fg   = lane >> 4;   // 4 face-groups per wave
  int pl   = lane & 15;   // 16 pixels per wave
  int gp   = blockIdx.x * 64 + wave * 16 + pl;   // global pixel 0..32767
  int b    = gp >> 12;
  int rem  = gp & 4095;
  int iy   = rem >> 6, ix = rem & 63;
  // xs=(2ix+1-64)/64, ys=(64-2iy-1)/64 : all ops exact (pow2 divide)
  float x = (2.0f*ix + 1.0f - 64.0f) * (1.0f/64.0f);
  float y = (64.0f - 2.0f*iy - 1.0f) * (1.0f/64.0f);

  float bestz = -1e10f;
  int   bestf = 0;
  float prod  = 1.0f;
  int   anyv  = 0;
  const float* fdb = fd + (size_t)b * NF * 12;

  for (int c0 = 0; c0 < NF; c0 += CHUNK) {
    __syncthreads();
    if (tid < CHUNK) {
      const float4* src = reinterpret_cast<const float4*>(fdb + (size_t)(c0 + tid)*12);
      float4 v0 = src[0];  // ax,ay,bx,by
      float4 v1 = src[1];  // cx,cy,det_safe,za
      float4 v2 = src[2];  // zb,zc,valid,pad
      float ax=v0.x, ay=v0.y, bx=v0.z, by=v0.w, cx=v1.x, cy=v1.y;
      float* d = sf[tid];
      d[0]=by-cy; d[1]=cx-bx; d[2]=cy-ay; d[3]=ax-cx;
      d[4]=cx; d[5]=cy; d[6]=v1.z; d[7]=v2.z;
      d[8]=v1.w; d[9]=v2.x; d[10]=v2.y; d[11]=0.0f;
      d[12]=fminf(fminf(ax,bx),cx)-FEXPAND; d[13]=fmaxf(fmaxf(ax,bx),cx)+FEXPAND;
      d[14]=fminf(fminf(ay,by),cy)-FEXPAND; d[15]=fmaxf(fmaxf(ay,by),cy)+FEXPAND;
      d[16]=ax; d[17]=ay; d[18]=bx; d[19]=by;
      float vx=bx-ax, vy=by-ay;
      d[20]=vx; d[21]=vy; d[22]=1.0f/(vx*vx+vy*vy+1e-12f); d[23]=0.0f;
      vx=cx-bx; vy=cy-by;
      d[24]=vx; d[25]=vy; d[26]=1.0f/(vx*vx+vy*vy+1e-12f); d[27]=0.0f;
      vx=ax-cx; vy=ay-cy;
      d[28]=vx; d[29]=vy; d[30]=1.0f/(vx*vx+vy*vy+1e-12f); d[31]=0.0f;
      d[32]=0.0f; d[33]=0.0f; d[34]=0.0f; d[35]=0.0f;
    }
    __syncthreads();

    for (int j = 0; j < CHUNK/4; ++j) {
      int l = (j << 2) | fg;          // interleave fgs -> adjacent LDS rows
      int g = c0 + l;                 // global face idx (ascending per lane)
      const float4* fl = reinterpret_cast<const float4*>(sf[l]);
      float4 bb = fl[3];
      // Outside the expanded bbox a face can contribute NEITHER to the
      // z-buffer (valid&covered => inside bbox) NOR to improb (contrib=0).
      bool inb = (x >= bb.x) && (x <= bb.y) && (y >= bb.z) && (y <= bb.w);
      if (!inb) continue;
      float4 E  = fl[0];
      float4 C  = fl[1];
      float4 Zv = fl[2];
      float w0,w1,w2,dxc,dyc;
      bary(E.x,E.y,E.z,E.w, C.z, C.x, C.y, x, y, w0,w1,w2,dxc,dyc);
      bool covered = (w0 >= 0.0f) && (w1 >= 0.0f) && (w2 >= 0.0f);
      bool valid   = covered && (C.w > 0.5f);
      float z = __fadd_rn(__fadd_rn(__fmul_rn(w0,Zv.x), __fmul_rn(w1,Zv.y)),
                          __fmul_rn(w2,Zv.z));
      float zval = valid ? z : -1e10f;
      if (zval > bestz) { bestz = zval; bestf = g; }
      anyv |= (int)valid;
      // soft edge distance (smooth path: fast math OK)
      float4 A4 = fl[4];
      float4 S1 = fl[5], S2 = fl[6], S3 = fl[7];
      float dxa = x - A4.x, dya = y - A4.y;
      float t = fminf(fmaxf((dxa*S1.x + dya*S1.y)*S1.z, 0.0f), 1.0f);
      float rx = dxa - t*S1.x, ry = dya - t*S1.y;
      float d2 = rx*rx + ry*ry;
      float dxb = x - A4.z, dyb = y - A4.w;
      t = fminf(fmaxf((dxb*S2.x + dyb*S2.y)*S2.z, 0.0f), 1.0f);
      rx = dxb - t*S2.x; ry = dyb - t*S2.y;
      d2 = fminf(d2, rx*rx + ry*ry);
      t = fminf(fmaxf((dxc*S3.x + dyc*S3.y)*S3.z, 0.0f), 1.0f);
      rx = dxc - t*S3.x; ry = dyc - t*S3.y;
      d2 = fminf(d2, rx*rx + ry*ry);
      d2 = covered ? 0.0f : d2;
      prod *= (1.0f - __expf(d2 * -142.85714285714286f));  // -(1e6/7000)*d2
    }
  }

  // combine the 4 face-groups (lane bits 4,5): max-z with first-index tiebreak,
  // product of survival probs, any-valid
  for (int off = 16; off < 64; off <<= 1) {
    float oz = __shfl_xor(bestz, off, 64);
    int   of = __shfl_xor(bestf, off, 64);
    float op = __shfl_xor(prod,  off, 64);
    int   oa = __shfl_xor(anyv,  off, 64);
    if (oz > bestz || (oz == bestz && of < bestf)) { bestz = oz; bestf = of; }
    prod *= op;
    anyv |= oa;
  }

  if (fg == 0) {
    // recompute winner's barycentrics bit-exactly (same ops as the loop)
    const float* o = fdb + (size_t)bestf * 12;
    float e0x = o[3]-o[5], e0y = o[4]-o[2], e1x = o[5]-o[1], e1y = o[0]-o[4];
    float w0,w1,w2,dxc,dyc;
    bary(e0x,e0y,e1x,e1y, o[6], o[4], o[5], x, y, w0,w1,w2,dxc,dyc);
    const int* fi = faces + ((size_t)b*NF + bestf)*3;
    const float* cb = colors + (size_t)b*NP*3;
    int i0 = fi[0], i1 = fi[1], i2 = fi[2];
    float fr = w0*cb[i0*3+0] + w1*cb[i1*3+0] + w2*cb[i2*3+0];
    float fg_ = w0*cb[i0*3+1] + w1*cb[i1*3+1] + w2*cb[i2*3+1];
    float fb = w0*cb[i0*3+2] + w1*cb[i1*3+2] + w2*cb[i2*3+2];
    float fa = __fadd_rn(__fadd_rn(w0, w1), w2);
    out[IMG_OFF + (size_t)gp*3 + 0] = anyv ? fr  : 0.0f;
    out[IMG_OFF + (size_t)gp*3 + 1] = anyv ? fg_ : 0.0f;
    out[IMG_OFF + (size_t)gp*3 + 2] = anyv ? fb  : 0.0f;
    out[PROB_OFF + gp] = 1.0f - prod;
    out[MASK_OFF + gp] = anyv ? fa : 0.0f;
  }
}

extern "C" void kernel_launch(void* const* d_in, const int* in_sizes, int n_in,
                              void* d_out, int out_size, void* d_ws, size_t ws_size,
                              hipStream_t stream) {
  const float* verts  = (const float*)d_in[0];
  const int*   faces  = (const int*)  d_in[1];
  const float* rot    = (const float*)d_in[2];
  const float* pos    = (const float*)d_in[3];
  const float* proj   = (const float*)d_in[4];
  const float* colors = (const float*)d_in[5];
  float* out = (float*)d_out;
  float* fd  = (float*)d_ws;   // NB*NF*12 floats = 192 KiB

  hipLaunchKernelGGL(face_setup, dim3((NB*NF)/256), dim3(256), 0, stream,
                     verts, faces, rot, pos, proj, fd);
  hipLaunchKernelGGL(normals_out, dim3((NB*NF)/256), dim3(256), 0, stream,
                     verts, faces, rot, pos, out + NRM_OFF);
  hipLaunchKernelGGL(raster, dim3((NB*NH*NW)/64), dim3(256), 0, stream,
                     fd, faces, colors, out);
}

// Round 5
// 107.353 us; speedup vs baseline: 1.0919x; 1.0919x over previous
//
#include <hip/hip_runtime.h>
#include <math.h>

#define NB 8
#define NP 512
#define NF 512
#define NH 64
#define NW 64
#define FEXPAND 0.02f
#define FEPS 1e-10f

#define IMG_OFF 0
#define PROB_OFF (NB*NH*NW*3)            /* 98304  */
#define NRM_OFF  (PROB_OFF + NB*NH*NW)   /* 131072 */
#define MASK_OFF (NRM_OFF + NB*NF*3)     /* 143360 */

// Barycentric weights, bit-exact vs the golden's f32 elementwise evaluation.
// No FMA contraction (sign decides coverage -> discrete output flips).
__device__ __forceinline__ void bary(float e0x, float e0y, float e1x, float e1y,
                                     float det_safe, float cx, float cy,
                                     float x, float y,
                                     float& w0, float& w1, float& w2,
                                     float& dxc, float& dyc) {
  dxc = x - cx; dyc = y - cy;
  float n0 = __fadd_rn(__fmul_rn(e0x, dxc), __fmul_rn(e0y, dyc));
  float n1 = __fadd_rn(__fmul_rn(e1x, dxc), __fmul_rn(e1y, dyc));
  w0 = __fdiv_rn(n0, det_safe);
  w1 = __fdiv_rn(n1, det_safe);
  w2 = __fsub_rn(__fsub_rn(1.0f, w0), w1);
}

#define CHUNK 128

// One fused kernel. Grid 2048 blocks x 256 threads.
// Block  = 16 pixels (one row segment) of batch b = blockIdx>>8.
// Waves  = 4 face-slices (wave w handles faces [w*32,(w+1)*32) of each chunk).
// Lanes  = 16 pixels x 4 face-groups (interleaved, conflict-free LDS rows).
// Each block redundantly computes the 512 face records into its own LDS
// (256x redundancy ~= 1.3us VALU + 1.4us L2 chip-wide -- cheap vs +2 launches).
// Blocks with blockIdx%256==0 additionally write normal1 for their batch.
// Bit-critical paths copied verbatim from the r4-passing kernels:
//   - pcam/screen/det/valid: exact __f*_rn, no FMA
//   - normal1: FMA-contracted cross  n_i = fmaf(a1,b2,-fl(a2*b1))  (XLA)
//   - winner w0/w1/w2 saved at z-update time == r4's bit-identical recompute
__global__ __launch_bounds__(256, 8) void render_all(
    const float* __restrict__ verts, const int* __restrict__ faces,
    const float* __restrict__ rot, const float* __restrict__ pos,
    const float* __restrict__ proj, const float* __restrict__ colors,
    float* __restrict__ out)
{
  __shared__ __align__(16) float sf[CHUNK][36];
  int tid  = threadIdx.x;
  int wave = tid >> 6;          // face-slice 0..3
  int lane = tid & 63;
  int fg   = lane >> 4;         // 4 face-groups per wave
  int pl   = lane & 15;         // 16 pixels per wave
  int gp   = blockIdx.x * 16 + pl;
  int b    = blockIdx.x >> 8;   // 256 blocks per batch
  int rem  = gp & 4095;
  int iy   = rem >> 6, ix = rem & 63;
  // xs=(2ix+1-64)/64, ys=(64-2iy-1)/64 : all ops exact (pow2 divide)
  float x = (2.0f*ix + 1.0f - 64.0f) * (1.0f/64.0f);
  float y = (64.0f - 2.0f*iy - 1.0f) * (1.0f/64.0f);
  bool norm_write = ((blockIdx.x & 255) == 0);

  float bestz = -1e10f;
  int   bestf = 0;
  float bw0 = 0.0f, bw1 = 0.0f, bw2 = 0.0f;
  float prod  = 1.0f;
  int   anyv  = 0;

  for (int c0 = 0; c0 < NF; c0 += CHUNK) {
    __syncthreads();
    if (tid < CHUNK) {
      int fidx = c0 + tid;
      int t = b * NF + fidx;
      float p0 = proj[0], p1 = proj[1], p2 = proj[2];
      float R0=rot[b*9+0],R1=rot[b*9+1],R2=rot[b*9+2];
      float R3=rot[b*9+3],R4=rot[b*9+4],R5=rot[b*9+5];
      float R6=rot[b*9+6],R7=rot[b*9+7],R8=rot[b*9+8];
      float ppx=pos[b*3+0], ppy=pos[b*3+1], ppz=pos[b*3+2];
      int idxs[3] = { faces[t*3+0], faces[t*3+1], faces[t*3+2] };
      float X[3],Y[3],Z[3],SX[3],SY[3];
#pragma unroll
      for (int k = 0; k < 3; ++k) {
        const float* v = verts + ((size_t)b*NP + idxs[k])*3;
        float dx = v[0]-ppx, dy = v[1]-ppy, dz = v[2]-ppz;
        float pcx = __fadd_rn(__fadd_rn(__fmul_rn(R0,dx),__fmul_rn(R1,dy)),__fmul_rn(R2,dz));
        float pcy = __fadd_rn(__fadd_rn(__fmul_rn(R3,dx),__fmul_rn(R4,dy)),__fmul_rn(R5,dz));
        float pcz = __fadd_rn(__fadd_rn(__fmul_rn(R6,dx),__fmul_rn(R7,dy)),__fmul_rn(R8,dz));
        X[k]=pcx; Y[k]=pcy; Z[k]=pcz;
        float dn = __fmul_rn(pcz, p2);
        SX[k] = __fdiv_rn(__fmul_rn(pcx, p0), dn);
        SY[k] = __fdiv_rn(__fmul_rn(pcy, p1), dn);
      }
      float e1x=X[1]-X[0], e1y=Y[1]-Y[0], e1z=Z[1]-Z[0];
      float e2x=X[2]-X[0], e2y=Y[2]-Y[0], e2z=Z[2]-Z[0];
      // valid gate: ELEMENTWISE nz (verified passing r4)
      float nzel = __fsub_rn(__fmul_rn(e1x,e2y), __fmul_rn(e1y,e2x));
      if (norm_write) {
        // normal1 output: FMA-contracted cross (verified passing r4)
        float m0 = __fmul_rn(e1z, e2y); float nxf = __fmaf_rn(e1y, e2z, -m0);
        float m1 = __fmul_rn(e1x, e2z); float nyf = __fmaf_rn(e1z, e2x, -m1);
        float m2 = __fmul_rn(e1y, e2x); float nzf = __fmaf_rn(e1x, e2y, -m2);
        float nn = __fsqrt_rn(__fadd_rn(__fadd_rn(__fmul_rn(nxf,nxf),__fmul_rn(nyf,nyf)),
                                        __fmul_rn(nzf,nzf)));
        float den = __fadd_rn(nn, 1e-12f);
        out[NRM_OFF + (size_t)t*3+0] = __fdiv_rn(nxf, den);
        out[NRM_OFF + (size_t)t*3+1] = __fdiv_rn(nyf, den);
        out[NRM_OFF + (size_t)t*3+2] = __fdiv_rn(nzf, den);
      }
      float ax=SX[0],ay=SY[0],bx=SX[1],by=SY[1],cx=SX[2],cy=SY[2];
      float det = __fadd_rn(__fmul_rn(__fsub_rn(by,cy),__fsub_rn(ax,cx)),
                            __fmul_rn(__fsub_rn(cx,bx),__fsub_rn(ay,cy)));
      float det_safe = (fabsf(det) < FEPS) ? FEPS : det;
      float validf = ((nzel > 0.0f) && (fabsf(det) > FEPS)) ? 1.0f : 0.0f;
      float* d = sf[tid];
      d[0]=by-cy; d[1]=cx-bx; d[2]=cy-ay; d[3]=ax-cx;
      d[4]=cx; d[5]=cy; d[6]=det_safe; d[7]=validf;
      d[8]=Z[0]; d[9]=Z[1]; d[10]=Z[2]; d[11]=0.0f;
      d[12]=fminf(fminf(ax,bx),cx)-FEXPAND; d[13]=fmaxf(fmaxf(ax,bx),cx)+FEXPAND;
      d[14]=fminf(fminf(ay,by),cy)-FEXPAND; d[15]=fmaxf(fmaxf(ay,by),cy)+FEXPAND;
      d[16]=ax; d[17]=ay; d[18]=bx; d[19]=by;
      float vx=bx-ax, vy=by-ay;
      d[20]=vx; d[21]=vy; d[22]=1.0f/(vx*vx+vy*vy+1e-12f); d[23]=0.0f;
      vx=cx-bx; vy=cy-by;
      d[24]=vx; d[25]=vy; d[26]=1.0f/(vx*vx+vy*vy+1e-12f); d[27]=0.0f;
      vx=ax-cx; vy=ay-cy;
      d[28]=vx; d[29]=vy; d[30]=1.0f/(vx*vx+vy*vy+1e-12f); d[31]=0.0f;
      d[32]=0.0f; d[33]=0.0f; d[34]=0.0f; d[35]=0.0f;
    }
    __syncthreads();

    // slice 'wave' covers chunk-local faces [wave*32, wave*32+32), fg-interleaved
    for (int j = 0; j < 8; ++j) {
      int l = wave*32 + (j << 2) + fg;
      int g = c0 + l;               // global face idx
      const float4* fl = reinterpret_cast<const float4*>(sf[l]);
      float4 bb = fl[3];
      bool inb = (x >= bb.x) && (x <= bb.y) && (y >= bb.z) && (y <= bb.w);
      if (!inb) continue;
      float4 E  = fl[0];
      float4 C  = fl[1];
      float4 Zv = fl[2];
      float w0,w1,w2,dxc,dyc;
      bary(E.x,E.y,E.z,E.w, C.z, C.x, C.y, x, y, w0,w1,w2,dxc,dyc);
      bool covered = (w0 >= 0.0f) && (w1 >= 0.0f) && (w2 >= 0.0f);
      bool valid   = covered && (C.w > 0.5f);
      float z = __fadd_rn(__fadd_rn(__fmul_rn(w0,Zv.x), __fmul_rn(w1,Zv.y)),
                          __fmul_rn(w2,Zv.z));
      float zval = valid ? z : -1e10f;
      if (zval > bestz) { bestz = zval; bestf = g; bw0 = w0; bw1 = w1; bw2 = w2; }
      anyv |= (int)valid;
      float4 A4 = fl[4];
      float4 S1 = fl[5], S2 = fl[6], S3 = fl[7];
      float dxa = x - A4.x, dya = y - A4.y;
      float t = fminf(fmaxf((dxa*S1.x + dya*S1.y)*S1.z, 0.0f), 1.0f);
      float rx = dxa - t*S1.x, ry = dya - t*S1.y;
      float d2 = rx*rx + ry*ry;
      float dxb = x - A4.z, dyb = y - A4.w;
      t = fminf(fmaxf((dxb*S2.x + dyb*S2.y)*S2.z, 0.0f), 1.0f);
      rx = dxb - t*S2.x; ry = dyb - t*S2.y;
      d2 = fminf(d2, rx*rx + ry*ry);
      t = fminf(fmaxf((dxc*S3.x + dyc*S3.y)*S3.z, 0.0f), 1.0f);
      rx = dxc - t*S3.x; ry = dyc - t*S3.y;
      d2 = fminf(d2, rx*rx + ry*ry);
      d2 = covered ? 0.0f : d2;
      prod *= (1.0f - __expf(d2 * -142.85714285714286f));  // -(1e6/7000)*d2
    }
  }

  // combine the 4 face-groups within the wave (lane bits 4,5)
  for (int off = 16; off < 64; off <<= 1) {
    float oz = __shfl_xor(bestz, off, 64);
    int   of = __shfl_xor(bestf, off, 64);
    float op = __shfl_xor(prod,  off, 64);
    int   oa = __shfl_xor(anyv,  off, 64);
    float o0 = __shfl_xor(bw0,   off, 64);
    float o1 = __shfl_xor(bw1,   off, 64);
    float o2 = __shfl_xor(bw2,   off, 64);
    if (oz > bestz || (oz == bestz && of < bestf)) {
      bestz = oz; bestf = of; bw0 = o0; bw1 = o1; bw2 = o2;
    }
    prod *= op;
    anyv |= oa;
  }

  // cross-wave (face-slice) combine via LDS (reuse sf space after barrier)
  __syncthreads();
  float* comb = &sf[0][0];     // [4 slices][16 pixels][8 floats] = 2 KiB
  if (fg == 0) {
    float* cc = comb + (size_t)(wave*16 + pl)*8;
    cc[0]=bestz; cc[1]=__int_as_float(bestf); cc[2]=prod; cc[3]=anyv?1.0f:0.0f;
    cc[4]=bw0; cc[5]=bw1; cc[6]=bw2; cc[7]=0.0f;
  }
  __syncthreads();
  if (tid < 16) {
    const float* c0p = comb + (size_t)tid*8;
    float bz = c0p[0]; int bf = __float_as_int(c0p[1]);
    float pr = c0p[2]; int av = (c0p[3] != 0.0f);
    float w0 = c0p[4], w1 = c0p[5], w2 = c0p[6];
    for (int s = 1; s < 4; ++s) {
      const float* cs = comb + (size_t)(s*16 + tid)*8;
      float oz = cs[0]; int of = __float_as_int(cs[1]);
      if (oz > bz || (oz == bz && of < bf)) { bz = oz; bf = of; w0 = cs[4]; w1 = cs[5]; w2 = cs[6]; }
      pr *= cs[2];
      av |= (cs[3] != 0.0f);
    }
    int t = b * NF + bf;
    const int* fi = faces + (size_t)t*3;
    const float* cb = colors + (size_t)b*NP*3;
    int i0 = fi[0], i1 = fi[1], i2 = fi[2];
    float fr  = w0*cb[i0*3+0] + w1*cb[i1*3+0] + w2*cb[i2*3+0];
    float fgc = w0*cb[i0*3+1] + w1*cb[i1*3+1] + w2*cb[i2*3+1];
    float fb  = w0*cb[i0*3+2] + w1*cb[i1*3+2] + w2*cb[i2*3+2];
    float fa  = __fadd_rn(__fadd_rn(w0, w1), w2);
    int gpp = blockIdx.x * 16 + tid;
    out[IMG_OFF + (size_t)gpp*3 + 0] = av ? fr  : 0.0f;
    out[IMG_OFF + (size_t)gpp*3 + 1] = av ? fgc : 0.0f;
    out[IMG_OFF + (size_t)gpp*3 + 2] = av ? fb  : 0.0f;
    out[PROB_OFF + gpp] = 1.0f - pr;
    out[MASK_OFF + gpp] = av ? fa : 0.0f;
  }
}

extern "C" void kernel_launch(void* const* d_in, const int* in_sizes, int n_in,
                              void* d_out, int out_size, void* d_ws, size_t ws_size,
                              hipStream_t stream) {
  const float* verts  = (const float*)d_in[0];
  const int*   faces  = (const int*)  d_in[1];
  const float* rot    = (const float*)d_in[2];
  const float* pos    = (const float*)d_in[3];
  const float* proj   = (const float*)d_in[4];
  const float* colors = (const float*)d_in[5];
  float* out = (float*)d_out;
  (void)d_ws; (void)ws_size;

  hipLaunchKernelGGL(render_all, dim3(NB*NH*NW/16), dim3(256), 0, stream,
                     verts, faces, rot, pos, proj, colors, out);
}

// Round 8
// 94.092 us; speedup vs baseline: 1.2458x; 1.1409x over previous
//
#include <hip/hip_runtime.h>
#include <math.h>

#define NB 8
#define NP 512
#define NF 512
#define NH 64
#define NW 64
#define FEXPAND 0.02f
#define FEPS 1e-10f

#define IMG_OFF 0
#define PROB_OFF (NB*NH*NW*3)            /* 98304  */
#define NRM_OFF  (PROB_OFF + NB*NH*NW)   /* 131072 */
#define MASK_OFF (NRM_OFF + NB*NF*3)     /* 143360 */

// Barycentric weights, bit-exact vs the golden's f32 elementwise evaluation.
// No FMA contraction (sign decides coverage -> discrete output flips).
__device__ __forceinline__ void bary(float e0x, float e0y, float e1x, float e1y,
                                     float det_safe, float cx, float cy,
                                     float x, float y,
                                     float& w0, float& w1, float& w2,
                                     float& dxc, float& dyc) {
  dxc = x - cx; dyc = y - cy;
  float n0 = __fadd_rn(__fmul_rn(e0x, dxc), __fmul_rn(e0y, dyc));
  float n1 = __fadd_rn(__fmul_rn(e1x, dxc), __fmul_rn(e1y, dyc));
  w0 = __fdiv_rn(n0, det_safe);
  w1 = __fdiv_rn(n1, det_safe);
  w2 = __fsub_rn(__fsub_rn(1.0f, w0), w1);
}

// One kernel. 512 blocks x 1024 threads (16 waves; 2 blocks/CU -> 32 waves/CU).
// Block = 8x8 pixel tile of batch b. Wave w = face-slice {f : f mod 16 == w}.
// Lane = pixel (8x8). Square tile -> f_wave ~= 0.27 (vs 0.70 for the r5
// 4-face x 16-px-strip packing), lane activity ~55%. Records built once into
// LDS by threads 0..511 (1 barrier), then a BARRIER-FREE face scan with
// prefetched bbox (read f+16's bbox before processing f). LDS reads are
// wave-uniform -> broadcast, conflict-free. No intra-wave reduction (lane=px);
// cross-slice combine via aliased LDS (stride 7 = conflict-free), 2 barriers.
// Bit-critical paths verbatim from the r4/r5-passing kernels:
//  - pcam/screen/det/valid: exact __f*_rn, no FMA
//  - normal1: FMA-contracted cross n_i = fmaf(a1,b2,-fl(a2*b1)) (XLA golden)
//  - winner w0/w1/w2 saved at z-update; anyv == (bestz != -1e10f) exactly
// Record layout (20 floats, 80 B, float4-aligned):
//  [0..3] ax,ay,bx,by  [4..7] cx,cy,det_safe,valid  [8..11] za,zb,zc,invLAB
//  [12..15] xmin,xmax,ymin,ymax  [16..19] invLBC,invLCA,pad,pad
__global__ __launch_bounds__(1024, 8) void render_all(
    const float* __restrict__ verts, const int* __restrict__ faces,
    const float* __restrict__ rot, const float* __restrict__ pos,
    const float* __restrict__ proj, const float* __restrict__ colors,
    float* __restrict__ out)
{
  __shared__ __align__(16) float smem[NF*20];   // 40 KiB; combine buf aliased
  int tid  = threadIdx.x;
  int b    = blockIdx.x >> 6;    // 64 tiles per batch
  int tile = blockIdx.x & 63;
  int wave = tid >> 6;           // face-slice 0..15
  int lane = tid & 63;           // pixel within 8x8 tile
  int ix = (tile & 7)*8 + (lane & 7);
  int iy = (tile >> 3)*8 + (lane >> 3);
  // xs=(2ix+1-64)/64, ys=(64-2iy-1)/64 : all ops exact (pow2 divide)
  float x = (2.0f*ix + 1.0f - 64.0f) * (1.0f/64.0f);
  float y = (64.0f - 2.0f*iy - 1.0f) * (1.0f/64.0f);

  if (tid < NF) {
    int t = b * NF + tid;
    float p0 = proj[0], p1 = proj[1], p2 = proj[2];
    float R0=rot[b*9+0],R1=rot[b*9+1],R2=rot[b*9+2];
    float R3=rot[b*9+3],R4=rot[b*9+4],R5=rot[b*9+5];
    float R6=rot[b*9+6],R7=rot[b*9+7],R8=rot[b*9+8];
    float ppx=pos[b*3+0], ppy=pos[b*3+1], ppz=pos[b*3+2];
    int idxs[3] = { faces[t*3+0], faces[t*3+1], faces[t*3+2] };
    float X[3],Y[3],Z[3],SX[3],SY[3];
#pragma unroll
    for (int k = 0; k < 3; ++k) {
      const float* v = verts + ((size_t)b*NP + idxs[k])*3;
      float dx = v[0]-ppx, dy = v[1]-ppy, dz = v[2]-ppz;
      float pcx = __fadd_rn(__fadd_rn(__fmul_rn(R0,dx),__fmul_rn(R1,dy)),__fmul_rn(R2,dz));
      float pcy = __fadd_rn(__fadd_rn(__fmul_rn(R3,dx),__fmul_rn(R4,dy)),__fmul_rn(R5,dz));
      float pcz = __fadd_rn(__fadd_rn(__fmul_rn(R6,dx),__fmul_rn(R7,dy)),__fmul_rn(R8,dz));
      X[k]=pcx; Y[k]=pcy; Z[k]=pcz;
      float dn = __fmul_rn(pcz, p2);
      SX[k] = __fdiv_rn(__fmul_rn(pcx, p0), dn);
      SY[k] = __fdiv_rn(__fmul_rn(pcy, p1), dn);
    }
    float e1x=X[1]-X[0], e1y=Y[1]-Y[0], e1z=Z[1]-Z[0];
    float e2x=X[2]-X[0], e2y=Y[2]-Y[0], e2z=Z[2]-Z[0];
    // valid gate: ELEMENTWISE nz (verified r4/r5)
    float nzel = __fsub_rn(__fmul_rn(e1x,e2y), __fmul_rn(e1y,e2x));
    if (tile == 0) {
      // normal1 output: FMA-contracted cross (verified r4/r5)
      float m0 = __fmul_rn(e1z, e2y); float nxf = __fmaf_rn(e1y, e2z, -m0);
      float m1 = __fmul_rn(e1x, e2z); float nyf = __fmaf_rn(e1z, e2x, -m1);
      float m2 = __fmul_rn(e1y, e2x); float nzf = __fmaf_rn(e1x, e2y, -m2);
      float nn = __fsqrt_rn(__fadd_rn(__fadd_rn(__fmul_rn(nxf,nxf),__fmul_rn(nyf,nyf)),
                                      __fmul_rn(nzf,nzf)));
      float den = __fadd_rn(nn, 1e-12f);
      out[NRM_OFF + (size_t)t*3+0] = __fdiv_rn(nxf, den);
      out[NRM_OFF + (size_t)t*3+1] = __fdiv_rn(nyf, den);
      out[NRM_OFF + (size_t)t*3+2] = __fdiv_rn(nzf, den);
    }
    float ax=SX[0],ay=SY[0],bx=SX[1],by=SY[1],cx=SX[2],cy=SY[2];
    float det = __fadd_rn(__fmul_rn(__fsub_rn(by,cy),__fsub_rn(ax,cx)),
                          __fmul_rn(__fsub_rn(cx,bx),__fsub_rn(ay,cy)));
    float det_safe = (fabsf(det) < FEPS) ? FEPS : det;
    float validf = ((nzel > 0.0f) && (fabsf(det) > FEPS)) ? 1.0f : 0.0f;
    float* d = &smem[tid*20];
    d[0]=ax; d[1]=ay; d[2]=bx; d[3]=by;
    d[4]=cx; d[5]=cy; d[6]=det_safe; d[7]=validf;
    d[8]=Z[0]; d[9]=Z[1]; d[10]=Z[2];
    float vx=bx-ax, vy=by-ay;
    d[11]=1.0f/(vx*vx+vy*vy+1e-12f);
    d[12]=fminf(fminf(ax,bx),cx)-FEXPAND; d[13]=fmaxf(fmaxf(ax,bx),cx)+FEXPAND;
    d[14]=fminf(fminf(ay,by),cy)-FEXPAND; d[15]=fmaxf(fmaxf(ay,by),cy)+FEXPAND;
    vx=cx-bx; vy=cy-by;
    d[16]=1.0f/(vx*vx+vy*vy+1e-12f);
    vx=ax-cx; vy=ay-cy;
    d[17]=1.0f/(vx*vx+vy*vy+1e-12f);
    d[18]=0.0f; d[19]=0.0f;
  }
  __syncthreads();

  float bestz = -1e10f;
  int   bestf = 0;
  float bw0 = 0.0f, bw1 = 0.0f, bw2 = 0.0f;
  float prod  = 1.0f;

  // prefetch first bbox; inside the loop prefetch f+16 before processing f
  float4 bb = *(const float4*)&smem[wave*20 + 12];
  for (int j = 0; j < 32; ++j) {
    int f = (j << 4) + wave;
    float4 bbn = bb;
    if (j < 31) bbn = *(const float4*)&smem[(f + 16)*20 + 12];
    bool inb = (x >= bb.x) && (x <= bb.y) && (y >= bb.z) && (y <= bb.w);
    if (__any(inb)) {
      const float* r = &smem[f*20];
      float4 q0 = *(const float4*)(r);       // ax,ay,bx,by
      float4 q1 = *(const float4*)(r + 4);   // cx,cy,det_safe,valid
      float4 q2 = *(const float4*)(r + 8);   // za,zb,zc,invLAB
      float iBC = r[16], iCA = r[17];
      float ax=q0.x, ay=q0.y, bxx=q0.z, byy=q0.w, cx=q1.x, cy=q1.y;
      // same lone-sub ops as r5's setup-stored values -> identical bits
      float e0x=__fsub_rn(byy,cy), e0y=__fsub_rn(cx,bxx);
      float e1x=__fsub_rn(cy,ay),  e1y=__fsub_rn(ax,cx);
      float w0,w1,w2,dxc,dyc;
      bary(e0x,e0y,e1x,e1y, q1.z, cx, cy, x, y, w0,w1,w2,dxc,dyc);
      bool covered = (w0 >= 0.0f) && (w1 >= 0.0f) && (w2 >= 0.0f);
      bool valid   = covered && (q1.w > 0.5f);
      float z = __fadd_rn(__fadd_rn(__fmul_rn(w0,q2.x), __fmul_rn(w1,q2.y)),
                          __fmul_rn(w2,q2.z));
      if (inb) {
        float zval = valid ? z : -1e10f;
        if (zval > bestz) { bestz = zval; bestf = f; bw0 = w0; bw1 = w1; bw2 = w2; }
        float dxa = x - ax, dya = y - ay;
        float vABx=__fsub_rn(bxx,ax), vABy=__fsub_rn(byy,ay);
        float t1 = fminf(fmaxf((dxa*vABx + dya*vABy)*q2.w, 0.0f), 1.0f);
        float rx = dxa - t1*vABx, ry = dya - t1*vABy;
        float d2 = rx*rx + ry*ry;
        float dxb = x - bxx, dyb = y - byy;
        float vBCx=__fsub_rn(cx,bxx), vBCy=__fsub_rn(cy,byy);
        t1 = fminf(fmaxf((dxb*vBCx + dyb*vBCy)*iBC, 0.0f), 1.0f);
        rx = dxb - t1*vBCx; ry = dyb - t1*vBCy;
        d2 = fminf(d2, rx*rx + ry*ry);
        float vCAx=__fsub_rn(ax,cx), vCAy=__fsub_rn(ay,cy);
        t1 = fminf(fmaxf((dxc*vCAx + dyc*vCAy)*iCA, 0.0f), 1.0f);
        rx = dxc - t1*vCAx; ry = dyc - t1*vCAy;
        d2 = fminf(d2, rx*rx + ry*ry);
        d2 = covered ? 0.0f : d2;
        prod *= (1.0f - __expf(d2 * -142.85714285714286f));  // -(1e6/7000)*d2
      }
    }
    bb = bbn;
  }

  __syncthreads();                 // records dead; alias combine buffer
  float* comb = smem;              // [16 slices][64 px][stride 7] = 28 KiB
  float* c = comb + (size_t)(wave*64 + lane)*7;
  c[0]=bestz; c[1]=__int_as_float(bestf); c[2]=prod;
  c[3]=bw0; c[4]=bw1; c[5]=bw2;
  __syncthreads();

  if (tid < 64) {
    const float* c0 = comb + (size_t)tid*7;
    float bz = c0[0]; int bf = __float_as_int(c0[1]); float pr = c0[2];
    float w0 = c0[3], w1 = c0[4], w2 = c0[5];
    for (int s = 1; s < 16; ++s) {
      const float* cs = comb + (size_t)(s*64 + tid)*7;
      float oz = cs[0]; int of = __float_as_int(cs[1]);
      if (oz > bz || (oz == bz && of < bf)) { bz = oz; bf = of; w0 = cs[3]; w1 = cs[4]; w2 = cs[5]; }
      pr *= cs[2];
    }
    int av = (bz != -1e10f);       // valid faces have z >> -1e10 (z in [-5,-1])
    int t = b * NF + bf;
    const int* fi = faces + (size_t)t*3;
    const float* cb = colors + (size_t)b*NP*3;
    int i0 = fi[0], i1 = fi[1], i2 = fi[2];
    float fr  = w0*cb[i0*3+0] + w1*cb[i1*3+0] + w2*cb[i2*3+0];
    float fgc = w0*cb[i0*3+1] + w1*cb[i1*3+1] + w2*cb[i2*3+1];
    float fb  = w0*cb[i0*3+2] + w1*cb[i1*3+2] + w2*cb[i2*3+2];
    float fa  = __fadd_rn(__fadd_rn(w0, w1), w2);
    int gp = b*4096 + iy*64 + ix;  // own lane's pixel (tid<64 -> wave 0)
    out[IMG_OFF + (size_t)gp*3 + 0] = av ? fr  : 0.0f;
    out[IMG_OFF + (size_t)gp*3 + 1] = av ? fgc : 0.0f;
    out[IMG_OFF + (size_t)gp*3 + 2] = av ? fb  : 0.0f;
    out[PROB_OFF + gp] = 1.0f - pr;
    out[MASK_OFF + gp] = av ? fa : 0.0f;
  }
}

extern "C" void kernel_launch(void* const* d_in, const int* in_sizes, int n_in,
                              void* d_out, int out_size, void* d_ws, size_t ws_size,
                              hipStream_t stream) {
  const float* verts  = (const float*)d_in[0];
  const int*   faces  = (const int*)  d_in[1];
  const float* rot    = (const float*)d_in[2];
  const float* pos    = (const float*)d_in[3];
  const float* proj   = (const float*)d_in[4];
  const float* colors = (const float*)d_in[5];
  float* out = (float*)d_out;
  (void)d_ws; (void)ws_size;

  hipLaunchKernelGGL(render_all, dim3(NB*64), dim3(1024), 0, stream,
                     verts, faces, rot, pos, proj, colors, out);
}

// Round 9
// 92.050 us; speedup vs baseline: 1.2734x; 1.0222x over previous
//
#include <hip/hip_runtime.h>
#include <math.h>

#define NB 8
#define NP 512
#define NF 512
#define NH 64
#define NW 64
#define FEXPAND 0.02f
#define FEPS 1e-10f

#define IMG_OFF 0
#define PROB_OFF (NB*NH*NW*3)            /* 98304  */
#define NRM_OFF  (PROB_OFF + NB*NH*NW)   /* 131072 */
#define MASK_OFF (NRM_OFF + NB*NF*3)     /* 143360 */

// One kernel. 512 blocks x 1024 threads (16 waves; 2 blocks/CU -> 32 waves/CU).
// Block = 8x8 pixel tile; wave w = face-slice {f mod 16 == w}; lane = pixel.
// v2 of the r8 structure, with EXACTNESS-PRESERVING adaptive skips:
//  - sign-precheck replaces w0>=0/w1>=0: sign(n)/sign(det_safe) match is
//    bit-equivalent (n is 0 or >=~1e-22, |det_safe|>=1e-10 -> no underflow
//    to -0; n==0 -> w=+-0 >= 0 always true). Divisions/w2/z run only under
//    __any(sign-pass).
//  - covered -> prod=0 latch: contrib=exp(-0)=1 -> prod*=0 == +0 exactly;
//    thereafter 0*[0,1) = +0 forever, so lanes with prod==0 skip seg_d2/exp
//    (bit-identical output).
// Bit-critical paths verbatim from the r4/r8-passing kernels:
//  - pcam/screen/det/valid: exact __f*_rn, no FMA
//  - normal1: FMA-contracted cross n_i = fmaf(a1,b2,-fl(a2*b1)) (XLA golden)
//  - winner w0/w1/w2 saved at z-update; anyv == (bestz != -1e10f)
// Record: 32 floats (128 B):
//  [0..3] e0x,e0y,e1x,e1y  [4..7] cx,cy,det_safe,validf  [8..11] za,zb,zc,invAB
//  [12..15] xmin,xmax,ymin,ymax  [16..19] ax,ay,bx,by
//  [20..23] vABx,vABy,vBCx,vBCy  [24..27] vCAx,vCAy,invBC,invCA  [28..31] pad
__global__ __launch_bounds__(1024, 8) void render_all(
    const float* __restrict__ verts, const int* __restrict__ faces,
    const float* __restrict__ rot, const float* __restrict__ pos,
    const float* __restrict__ proj, const float* __restrict__ colors,
    float* __restrict__ out)
{
  __shared__ __align__(16) float smem[NF*32];   // 64 KiB; combine buf aliased
  int tid  = threadIdx.x;
  int b    = blockIdx.x >> 6;    // 64 tiles per batch
  int tile = blockIdx.x & 63;
  int wave = tid >> 6;           // face-slice 0..15
  int lane = tid & 63;           // pixel within 8x8 tile
  int ix = (tile & 7)*8 + (lane & 7);
  int iy = (tile >> 3)*8 + (lane >> 3);
  // xs=(2ix+1-64)/64, ys=(64-2iy-1)/64 : all ops exact (pow2 divide)
  float x = (2.0f*ix + 1.0f - 64.0f) * (1.0f/64.0f);
  float y = (64.0f - 2.0f*iy - 1.0f) * (1.0f/64.0f);

  if (tid < NF) {
    int t = b * NF + tid;
    float p0 = proj[0], p1 = proj[1], p2 = proj[2];
    float R0=rot[b*9+0],R1=rot[b*9+1],R2=rot[b*9+2];
    float R3=rot[b*9+3],R4=rot[b*9+4],R5=rot[b*9+5];
    float R6=rot[b*9+6],R7=rot[b*9+7],R8=rot[b*9+8];
    float ppx=pos[b*3+0], ppy=pos[b*3+1], ppz=pos[b*3+2];
    int idxs[3] = { faces[t*3+0], faces[t*3+1], faces[t*3+2] };
    float X[3],Y[3],Z[3],SX[3],SY[3];
#pragma unroll
    for (int k = 0; k < 3; ++k) {
      const float* v = verts + ((size_t)b*NP + idxs[k])*3;
      float dx = v[0]-ppx, dy = v[1]-ppy, dz = v[2]-ppz;
      float pcx = __fadd_rn(__fadd_rn(__fmul_rn(R0,dx),__fmul_rn(R1,dy)),__fmul_rn(R2,dz));
      float pcy = __fadd_rn(__fadd_rn(__fmul_rn(R3,dx),__fmul_rn(R4,dy)),__fmul_rn(R5,dz));
      float pcz = __fadd_rn(__fadd_rn(__fmul_rn(R6,dx),__fmul_rn(R7,dy)),__fmul_rn(R8,dz));
      X[k]=pcx; Y[k]=pcy; Z[k]=pcz;
      float dn = __fmul_rn(pcz, p2);
      SX[k] = __fdiv_rn(__fmul_rn(pcx, p0), dn);
      SY[k] = __fdiv_rn(__fmul_rn(pcy, p1), dn);
    }
    float e1x=X[1]-X[0], e1y=Y[1]-Y[0], e1z=Z[1]-Z[0];
    float e2x=X[2]-X[0], e2y=Y[2]-Y[0], e2z=Z[2]-Z[0];
    // valid gate: ELEMENTWISE nz (verified r4..r8)
    float nzel = __fsub_rn(__fmul_rn(e1x,e2y), __fmul_rn(e1y,e2x));
    if (tile == 0) {
      // normal1 output: FMA-contracted cross (verified r4..r8)
      float m0 = __fmul_rn(e1z, e2y); float nxf = __fmaf_rn(e1y, e2z, -m0);
      float m1 = __fmul_rn(e1x, e2z); float nyf = __fmaf_rn(e1z, e2x, -m1);
      float m2 = __fmul_rn(e1y, e2x); float nzf = __fmaf_rn(e1x, e2y, -m2);
      float nn = __fsqrt_rn(__fadd_rn(__fadd_rn(__fmul_rn(nxf,nxf),__fmul_rn(nyf,nyf)),
                                      __fmul_rn(nzf,nzf)));
      float den = __fadd_rn(nn, 1e-12f);
      out[NRM_OFF + (size_t)t*3+0] = __fdiv_rn(nxf, den);
      out[NRM_OFF + (size_t)t*3+1] = __fdiv_rn(nyf, den);
      out[NRM_OFF + (size_t)t*3+2] = __fdiv_rn(nzf, den);
    }
    float ax=SX[0],ay=SY[0],bx=SX[1],by=SY[1],cx=SX[2],cy=SY[2];
    float det = __fadd_rn(__fmul_rn(__fsub_rn(by,cy),__fsub_rn(ax,cx)),
                          __fmul_rn(__fsub_rn(cx,bx),__fsub_rn(ay,cy)));
    float det_safe = (fabsf(det) < FEPS) ? FEPS : det;
    float validf = ((nzel > 0.0f) && (fabsf(det) > FEPS)) ? 1.0f : 0.0f;
    float* d = &smem[tid*32];
    d[0]=__fsub_rn(by,cy); d[1]=__fsub_rn(cx,bx);
    d[2]=__fsub_rn(cy,ay); d[3]=__fsub_rn(ax,cx);
    d[4]=cx; d[5]=cy; d[6]=det_safe; d[7]=validf;
    d[8]=Z[0]; d[9]=Z[1]; d[10]=Z[2];
    float vx=bx-ax, vy=by-ay;
    d[11]=1.0f/(vx*vx+vy*vy+1e-12f);
    d[20]=vx; d[21]=vy;
    d[12]=fminf(fminf(ax,bx),cx)-FEXPAND; d[13]=fmaxf(fmaxf(ax,bx),cx)+FEXPAND;
    d[14]=fminf(fminf(ay,by),cy)-FEXPAND; d[15]=fmaxf(fmaxf(ay,by),cy)+FEXPAND;
    d[16]=ax; d[17]=ay; d[18]=bx; d[19]=by;
    vx=cx-bx; vy=cy-by;
    d[22]=vx; d[23]=vy; d[26]=1.0f/(vx*vx+vy*vy+1e-12f);
    vx=ax-cx; vy=ay-cy;
    d[24]=vx; d[25]=vy; d[27]=1.0f/(vx*vx+vy*vy+1e-12f);
    d[28]=0.0f; d[29]=0.0f; d[30]=0.0f; d[31]=0.0f;
  }
  __syncthreads();

  float bestz = -1e10f;
  int   bestf = 0;
  float bw0 = 0.0f, bw1 = 0.0f, bw2 = 0.0f;
  float prod  = 1.0f;

  // prefetch first bbox; inside the loop prefetch f+16 before processing f
  float4 bb = *(const float4*)&smem[wave*32 + 12];
  for (int j = 0; j < 32; ++j) {
    int f = (j << 4) + wave;
    float4 bbn = bb;
    if (j < 31) bbn = *(const float4*)&smem[(f + 16)*32 + 12];
    bool inb = (x >= bb.x) && (x <= bb.y) && (y >= bb.z) && (y <= bb.w);
    if (__any(inb)) {
      const float* r = &smem[f*32];
      float4 qe = *(const float4*)(r);       // e0x,e0y,e1x,e1y
      float4 q1 = *(const float4*)(r + 4);   // cx,cy,det_safe,validf
      float dxc = x - q1.x, dyc = y - q1.y;
      float n0 = __fadd_rn(__fmul_rn(qe.x, dxc), __fmul_rn(qe.y, dyc));
      float n1 = __fadd_rn(__fmul_rn(qe.z, dxc), __fmul_rn(qe.w, dyc));
      // exact sign-equivalent of (w0>=0 && w1>=0); see header proof
      bool dsp  = q1.z > 0.0f;
      bool pass = ((n0 == 0.0f) || ((n0 > 0.0f) == dsp)) &&
                  ((n1 == 0.0f) || ((n1 > 0.0f) == dsp));
      bool act = inb && pass;
      bool covered = false;
      if (__any(act)) {
        float4 q2 = *(const float4*)(r + 8); // za,zb,zc,invAB
        float w0 = __fdiv_rn(n0, q1.z);
        float w1 = __fdiv_rn(n1, q1.z);
        float w2 = __fsub_rn(__fsub_rn(1.0f, w0), w1);
        covered = act && (w2 >= 0.0f);
        bool valid = covered && (q1.w > 0.5f);
        float z = __fadd_rn(__fadd_rn(__fmul_rn(w0,q2.x), __fmul_rn(w1,q2.y)),
                            __fmul_rn(w2,q2.z));
        float zval = valid ? z : -1e10f;
        if (zval > bestz) { bestz = zval; bestf = f; bw0 = w0; bw1 = w1; bw2 = w2; }
      }
      if (covered) prod = 0.0f;              // == prod*(1-exp(-0)) exactly
      bool needd = inb && !covered && (prod != 0.0f);
      if (__any(needd)) {
        float4 qa = *(const float4*)(r + 16); // ax,ay,bx,by
        float4 qv = *(const float4*)(r + 20); // vABx,vABy,vBCx,vBCy
        float4 qw = *(const float4*)(r + 24); // vCAx,vCAy,invBC,invCA
        float invAB = r[11];
        float dxa = x - qa.x, dya = y - qa.y;
        float t1 = fminf(fmaxf((dxa*qv.x + dya*qv.y)*invAB, 0.0f), 1.0f);
        float rx = dxa - t1*qv.x, ry = dya - t1*qv.y;
        float d2 = rx*rx + ry*ry;
        float dxb = x - qa.z, dyb = y - qa.w;
        t1 = fminf(fmaxf((dxb*qv.z + dyb*qv.w)*qw.z, 0.0f), 1.0f);
        rx = dxb - t1*qv.z; ry = dyb - t1*qv.w;
        d2 = fminf(d2, rx*rx + ry*ry);
        t1 = fminf(fmaxf((dxc*qw.x + dyc*qw.y)*qw.w, 0.0f), 1.0f);
        rx = dxc - t1*qw.x; ry = dyc - t1*qw.y;
        d2 = fminf(d2, rx*rx + ry*ry);
        if (needd)
          prod *= (1.0f - __expf(d2 * -142.85714285714286f));  // -(1e6/7000)*d2
      }
    }
    bb = bbn;
  }

  __syncthreads();                 // records dead; alias combine buffer
  float* comb = smem;              // [16 slices][64 px][stride 7] = 28 KiB
  float* c = comb + (size_t)(wave*64 + lane)*7;
  c[0]=bestz; c[1]=__int_as_float(bestf); c[2]=prod;
  c[3]=bw0; c[4]=bw1; c[5]=bw2;
  __syncthreads();

  if (tid < 64) {
    const float* c0 = comb + (size_t)tid*7;
    float bz = c0[0]; int bf = __float_as_int(c0[1]); float pr = c0[2];
    float w0 = c0[3], w1 = c0[4], w2 = c0[5];
    for (int s = 1; s < 16; ++s) {
      const float* cs = comb + (size_t)(s*64 + tid)*7;
      float oz = cs[0]; int of = __float_as_int(cs[1]);
      if (oz > bz || (oz == bz && of < bf)) { bz = oz; bf = of; w0 = cs[3]; w1 = cs[4]; w2 = cs[5]; }
      pr *= cs[2];
    }
    int av = (bz != -1e10f);       // valid faces have z >> -1e10 (z in [-5,-1])
    int t = b * NF + bf;
    const int* fi = faces + (size_t)t*3;
    const float* cb = colors + (size_t)b*NP*3;
    int i0 = fi[0], i1 = fi[1], i2 = fi[2];
    float fr  = w0*cb[i0*3+0] + w1*cb[i1*3+0] + w2*cb[i2*3+0];
    float fgc = w0*cb[i0*3+1] + w1*cb[i1*3+1] + w2*cb[i2*3+1];
    float fb  = w0*cb[i0*3+2] + w1*cb[i1*3+2] + w2*cb[i2*3+2];
    float fa  = __fadd_rn(__fadd_rn(w0, w1), w2);
    int gp = b*4096 + iy*64 + ix;  // own lane's pixel (tid<64 -> wave 0)
    out[IMG_OFF + (size_t)gp*3 + 0] = av ? fr  : 0.0f;
    out[IMG_OFF + (size_t)gp*3 + 1] = av ? fgc : 0.0f;
    out[IMG_OFF + (size_t)gp*3 + 2] = av ? fb  : 0.0f;
    out[PROB_OFF + gp] = 1.0f - pr;
    out[MASK_OFF + gp] = av ? fa : 0.0f;
  }
}

extern "C" void kernel_launch(void* const* d_in, const int* in_sizes, int n_in,
                              void* d_out, int out_size, void* d_ws, size_t ws_size,
                              hipStream_t stream) {
  const float* verts  = (const float*)d_in[0];
  const int*   faces  = (const int*)  d_in[1];
  const float* rot    = (const float*)d_in[2];
  const float* pos    = (const float*)d_in[3];
  const float* proj   = (const float*)d_in[4];
  const float* colors = (const float*)d_in[5];
  float* out = (float*)d_out;
  (void)d_ws; (void)ws_size;

  hipLaunchKernelGGL(render_all, dim3(NB*64), dim3(1024), 0, stream,
                     verts, faces, rot, pos, proj, colors, out);
}

// Round 10
// 89.462 us; speedup vs baseline: 1.3102x; 1.0289x over previous
//
#include <hip/hip_runtime.h>
#include <math.h>

#define NB 8
#define NP 512
#define NF 512
#define NH 64
#define NW 64
#define FEXPAND 0.02f
#define FEPS 1e-10f

#define IMG_OFF 0
#define PROB_OFF (NB*NH*NW*3)            /* 98304  */
#define NRM_OFF  (PROB_OFF + NB*NH*NW)   /* 131072 */
#define MASK_OFF (NRM_OFF + NB*NF*3)     /* 143360 */

// One kernel. 512 blocks x 1024 threads (16 waves; 2 blocks/CU).
// Block = 8x8 px tile; lane = pixel. NEW vs r9: per-tile FACE BINNING --
// threads 0..511 test each face's bbox against the tile's exact pixel-center
// rect (both exact f32 -> conservative superset of any per-pixel inb),
// ballot-compact indices into a globally ASCENDING flist (per-wave popcount +
// deterministic prefix offsets). Scan walks only the L~=100-180 list entries
// (16-way strided, each wave's sequence ascending -> first-index z-tiebreak
// preserved; prod reorder is ~1ulp, invisible at the bf16 compare floor).
// r9's exactness-preserving gates kept verbatim:
//  - sign-precheck == (w0>=0 && w1>=0) exactly (|n| 0 or >=~1e-22, |det|>=1e-10)
//  - covered -> prod=0 latch (== prod*(1-exp(-0)) exactly, absorbing forever)
// Bit-critical paths verbatim from r4..r9 passing kernels:
//  - pcam/screen/det/valid: exact __f*_rn, no FMA
//  - normal1: FMA-contracted cross n_i = fmaf(a1,b2,-fl(a2*b1)) (XLA golden)
//  - winner w0/w1/w2 saved at z-update; av == (bestz != -1e10f)
// Record: 28 floats (112 B = 7x16B, float4-aligned):
//  [0..3] e0x,e0y,e1x,e1y  [4..7] cx,cy,det_safe,validf  [8..11] za,zb,zc,invAB
//  [12..15] xmin,xmax,ymin,ymax  [16..19] ax,ay,bx,by
//  [20..23] vABx,vABy,vBCx,vBCy  [24..27] vCAx,vCAy,invBC,invCA
__global__ __launch_bounds__(1024, 8) void render_all(
    const float* __restrict__ verts, const int* __restrict__ faces,
    const float* __restrict__ rot, const float* __restrict__ pos,
    const float* __restrict__ proj, const float* __restrict__ colors,
    float* __restrict__ out)
{
  __shared__ __align__(16) float smem[NF*28];   // 56 KiB; combine buf aliased
  __shared__ unsigned short flist[NF];
  __shared__ int wcnt[8];
  __shared__ int Ltot;
  int tid  = threadIdx.x;
  int b    = blockIdx.x >> 6;    // 64 tiles per batch
  int tile = blockIdx.x & 63;
  int wave = tid >> 6;           // 16 waves
  int lane = tid & 63;           // pixel within 8x8 tile
  int ix0 = (tile & 7)*8, iy0 = (tile >> 3)*8;
  int ix = ix0 + (lane & 7);
  int iy = iy0 + (lane >> 3);
  // xs=(2ix+1-64)/64, ys=(64-2iy-1)/64 : all ops exact (pow2 divide)
  float x = (2.0f*ix + 1.0f - 64.0f) * (1.0f/64.0f);
  float y = (64.0f - 2.0f*iy - 1.0f) * (1.0f/64.0f);
  // tile pixel-center rect (exact)
  float txlo = (2.0f*ix0 + 1.0f - 64.0f) * (1.0f/64.0f);
  float txhi = (2.0f*(ix0+7) + 1.0f - 64.0f) * (1.0f/64.0f);
  float tyhi = (64.0f - 2.0f*iy0 - 1.0f) * (1.0f/64.0f);
  float tylo = (64.0f - 2.0f*(iy0+7) - 1.0f) * (1.0f/64.0f);

  if (tid < NF) {
    int t = b * NF + tid;
    float p0 = proj[0], p1 = proj[1], p2 = proj[2];
    float R0=rot[b*9+0],R1=rot[b*9+1],R2=rot[b*9+2];
    float R3=rot[b*9+3],R4=rot[b*9+4],R5=rot[b*9+5];
    float R6=rot[b*9+6],R7=rot[b*9+7],R8=rot[b*9+8];
    float ppx=pos[b*3+0], ppy=pos[b*3+1], ppz=pos[b*3+2];
    int idxs[3] = { faces[t*3+0], faces[t*3+1], faces[t*3+2] };
    float X[3],Y[3],Z[3],SX[3],SY[3];
#pragma unroll
    for (int k = 0; k < 3; ++k) {
      const float* v = verts + ((size_t)b*NP + idxs[k])*3;
      float dx = v[0]-ppx, dy = v[1]-ppy, dz = v[2]-ppz;
      float pcx = __fadd_rn(__fadd_rn(__fmul_rn(R0,dx),__fmul_rn(R1,dy)),__fmul_rn(R2,dz));
      float pcy = __fadd_rn(__fadd_rn(__fmul_rn(R3,dx),__fmul_rn(R4,dy)),__fmul_rn(R5,dz));
      float pcz = __fadd_rn(__fadd_rn(__fmul_rn(R6,dx),__fmul_rn(R7,dy)),__fmul_rn(R8,dz));
      X[k]=pcx; Y[k]=pcy; Z[k]=pcz;
      float dn = __fmul_rn(pcz, p2);
      SX[k] = __fdiv_rn(__fmul_rn(pcx, p0), dn);
      SY[k] = __fdiv_rn(__fmul_rn(pcy, p1), dn);
    }
    float e1x=X[1]-X[0], e1y=Y[1]-Y[0], e1z=Z[1]-Z[0];
    float e2x=X[2]-X[0], e2y=Y[2]-Y[0], e2z=Z[2]-Z[0];
    // valid gate: ELEMENTWISE nz (verified r4..r9)
    float nzel = __fsub_rn(__fmul_rn(e1x,e2y), __fmul_rn(e1y,e2x));
    if (tile == 0) {
      // normal1 output: FMA-contracted cross (verified r4..r9)
      float m0 = __fmul_rn(e1z, e2y); float nxf = __fmaf_rn(e1y, e2z, -m0);
      float m1 = __fmul_rn(e1x, e2z); float nyf = __fmaf_rn(e1z, e2x, -m1);
      float m2 = __fmul_rn(e1y, e2x); float nzf = __fmaf_rn(e1x, e2y, -m2);
      float nn = __fsqrt_rn(__fadd_rn(__fadd_rn(__fmul_rn(nxf,nxf),__fmul_rn(nyf,nyf)),
                                      __fmul_rn(nzf,nzf)));
      float den = __fadd_rn(nn, 1e-12f);
      out[NRM_OFF + (size_t)t*3+0] = __fdiv_rn(nxf, den);
      out[NRM_OFF + (size_t)t*3+1] = __fdiv_rn(nyf, den);
      out[NRM_OFF + (size_t)t*3+2] = __fdiv_rn(nzf, den);
    }
    float ax=SX[0],ay=SY[0],bx=SX[1],by=SY[1],cx=SX[2],cy=SY[2];
    float det = __fadd_rn(__fmul_rn(__fsub_rn(by,cy),__fsub_rn(ax,cx)),
                          __fmul_rn(__fsub_rn(cx,bx),__fsub_rn(ay,cy)));
    float det_safe = (fabsf(det) < FEPS) ? FEPS : det;
    float validf = ((nzel > 0.0f) && (fabsf(det) > FEPS)) ? 1.0f : 0.0f;
    float* d = &smem[tid*28];
    d[0]=__fsub_rn(by,cy); d[1]=__fsub_rn(cx,bx);
    d[2]=__fsub_rn(cy,ay); d[3]=__fsub_rn(ax,cx);
    d[4]=cx; d[5]=cy; d[6]=det_safe; d[7]=validf;
    d[8]=Z[0]; d[9]=Z[1]; d[10]=Z[2];
    float vx=bx-ax, vy=by-ay;
    d[11]=1.0f/(vx*vx+vy*vy+1e-12f);
    d[20]=vx; d[21]=vy;
    d[12]=fminf(fminf(ax,bx),cx)-FEXPAND; d[13]=fmaxf(fmaxf(ax,bx),cx)+FEXPAND;
    d[14]=fminf(fminf(ay,by),cy)-FEXPAND; d[15]=fmaxf(fmaxf(ay,by),cy)+FEXPAND;
    d[16]=ax; d[17]=ay; d[18]=bx; d[19]=by;
    vx=cx-bx; vy=cy-by;
    d[22]=vx; d[23]=vy; d[26]=1.0f/(vx*vx+vy*vy+1e-12f);
    vx=ax-cx; vy=ay-cy;
    d[24]=vx; d[25]=vy; d[27]=1.0f/(vx*vx+vy*vy+1e-12f);
  }
  __syncthreads();

  // ---- per-tile binning (threads 0..511, 8 waves x 64 faces) ----
  bool pass = false;
  if (tid < NF) {
    const float* rr = &smem[tid*28 + 12];   // xmin,xmax,ymin,ymax
    pass = (rr[1] >= txlo) && (rr[0] <= txhi) && (rr[3] >= tylo) && (rr[2] <= tyhi);
  }
  unsigned long long m = __ballot(pass);
  if (tid < NF && (tid & 63) == 0) wcnt[tid >> 6] = __popcll(m);
  __syncthreads();
  if (tid < NF && pass) {
    int w8 = tid >> 6;
    int off = 0;
#pragma unroll
    for (int i = 0; i < 8; ++i) if (i < w8) off += wcnt[i];
    off += __popcll(m & ((1ull << (tid & 63)) - 1ull));
    flist[off] = (unsigned short)tid;
  }
  if (tid == 0) {
    int s = 0;
#pragma unroll
    for (int i = 0; i < 8; ++i) s += wcnt[i];
    Ltot = s;
  }
  __syncthreads();
  int L = Ltot;

  float bestz = -1e10f;
  int   bestf = 0;
  float bw0 = 0.0f, bw1 = 0.0f, bw2 = 0.0f;
  float prod  = 1.0f;

  // wave takes list entries wave, wave+16, ... (ascending per wave)
  int idx = wave;
  int fcur = (idx < L) ? (int)flist[idx] : 0;
  float4 bb = (idx < L) ? *(const float4*)&smem[fcur*28 + 12]
                        : make_float4(0.f,0.f,0.f,0.f);
  while (idx < L) {
    int nidx = idx + 16;
    int fnext = fcur;
    float4 bbn = bb;
    if (nidx < L) {
      fnext = (int)flist[nidx];
      bbn = *(const float4*)&smem[fnext*28 + 12];
    }
    int f = fcur;
    const float* r = &smem[f*28];
    bool inb = (x >= bb.x) && (x <= bb.y) && (y >= bb.z) && (y <= bb.w);
    bool covered = false;
    if (__any(inb)) {
      float4 qe = *(const float4*)(r);       // e0x,e0y,e1x,e1y
      float4 q1 = *(const float4*)(r + 4);   // cx,cy,det_safe,validf
      float dxc = x - q1.x, dyc = y - q1.y;
      float n0 = __fadd_rn(__fmul_rn(qe.x, dxc), __fmul_rn(qe.y, dyc));
      float n1 = __fadd_rn(__fmul_rn(qe.z, dxc), __fmul_rn(qe.w, dyc));
      // exact sign-equivalent of (w0>=0 && w1>=0); see header
      bool dsp  = q1.z > 0.0f;
      bool spass = ((n0 == 0.0f) || ((n0 > 0.0f) == dsp)) &&
                   ((n1 == 0.0f) || ((n1 > 0.0f) == dsp));
      bool act = inb && spass;
      if (__any(act)) {
        float4 q2 = *(const float4*)(r + 8); // za,zb,zc,invAB
        float w0 = __fdiv_rn(n0, q1.z);
        float w1 = __fdiv_rn(n1, q1.z);
        float w2 = __fsub_rn(__fsub_rn(1.0f, w0), w1);
        covered = act && (w2 >= 0.0f);
        bool valid = covered && (q1.w > 0.5f);
        float z = __fadd_rn(__fadd_rn(__fmul_rn(w0,q2.x), __fmul_rn(w1,q2.y)),
                            __fmul_rn(w2,q2.z));
        float zval = valid ? z : -1e10f;
        if (zval > bestz) { bestz = zval; bestf = f; bw0 = w0; bw1 = w1; bw2 = w2; }
      }
      if (covered) prod = 0.0f;              // == prod*(1-exp(-0)) exactly
      bool needd = inb && !covered && (prod != 0.0f);
      if (__any(needd)) {
        float4 qa = *(const float4*)(r + 16); // ax,ay,bx,by
        float4 qv = *(const float4*)(r + 20); // vABx,vABy,vBCx,vBCy
        float4 qw = *(const float4*)(r + 24); // vCAx,vCAy,invBC,invCA
        float invAB = r[11];
        float dxa = x - qa.x, dya = y - qa.y;
        float t1 = fminf(fmaxf((dxa*qv.x + dya*qv.y)*invAB, 0.0f), 1.0f);
        float rx = dxa - t1*qv.x, ry = dya - t1*qv.y;
        float d2 = rx*rx + ry*ry;
        float dxb = x - qa.z, dyb = y - qa.w;
        t1 = fminf(fmaxf((dxb*qv.z + dyb*qv.w)*qw.z, 0.0f), 1.0f);
        rx = dxb - t1*qv.z; ry = dyb - t1*qv.w;
        d2 = fminf(d2, rx*rx + ry*ry);
        t1 = fminf(fmaxf((dxc*qw.x + dyc*qw.y)*qw.w, 0.0f), 1.0f);
        rx = dxc - t1*qw.x; ry = dyc - t1*qw.y;
        d2 = fminf(d2, rx*rx + ry*ry);
        if (needd)
          prod *= (1.0f - __expf(d2 * -142.85714285714286f));  // -(1e6/7000)*d2
      }
    }
    idx = nidx; fcur = fnext; bb = bbn;
  }

  __syncthreads();                 // records dead; alias combine buffer
  float* comb = smem;              // [16 slices][64 px][stride 7] = 28 KiB
  float* c = comb + (size_t)(wave*64 + lane)*7;
  c[0]=bestz; c[1]=__int_as_float(bestf); c[2]=prod;
  c[3]=bw0; c[4]=bw1; c[5]=bw2;
  __syncthreads();

  if (tid < 64) {
    const float* c0 = comb + (size_t)tid*7;
    float bz = c0[0]; int bf = __float_as_int(c0[1]); float pr = c0[2];
    float w0 = c0[3], w1 = c0[4], w2 = c0[5];
    for (int s = 1; s < 16; ++s) {
      const float* cs = comb + (size_t)(s*64 + tid)*7;
      float oz = cs[0]; int of = __float_as_int(cs[1]);
      if (oz > bz || (oz == bz && of < bf)) { bz = oz; bf = of; w0 = cs[3]; w1 = cs[4]; w2 = cs[5]; }
      pr *= cs[2];
    }
    int av = (bz != -1e10f);       // valid faces have z >> -1e10 (z in [-5,-1])
    int t = b * NF + bf;
    const int* fi = faces + (size_t)t*3;
    const float* cb = colors + (size_t)b*NP*3;
    int i0 = fi[0], i1 = fi[1], i2 = fi[2];
    float fr  = w0*cb[i0*3+0] + w1*cb[i1*3+0] + w2*cb[i2*3+0];
    float fgc = w0*cb[i0*3+1] + w1*cb[i1*3+1] + w2*cb[i2*3+1];
    float fb  = w0*cb[i0*3+2] + w1*cb[i1*3+2] + w2*cb[i2*3+2];
    float fa  = __fadd_rn(__fadd_rn(w0, w1), w2);
    int gp = b*4096 + iy*64 + ix;  // own lane's pixel (tid<64 -> wave 0)
    out[IMG_OFF + (size_t)gp*3 + 0] = av ? fr  : 0.0f;
    out[IMG_OFF + (size_t)gp*3 + 1] = av ? fgc : 0.0f;
    out[IMG_OFF + (size_t)gp*3 + 2] = av ? fb  : 0.0f;
    out[PROB_OFF + gp] = 1.0f - pr;
    out[MASK_OFF + gp] = av ? fa : 0.0f;
  }
}

extern "C" void kernel_launch(void* const* d_in, const int* in_sizes, int n_in,
                              void* d_out, int out_size, void* d_ws, size_t ws_size,
                              hipStream_t stream) {
  const float* verts  = (const float*)d_in[0];
  const int*   faces  = (const int*)  d_in[1];
  const float* rot    = (const float*)d_in[2];
  const float* pos    = (const float*)d_in[3];
  const float* proj   = (const float*)d_in[4];
  const float* colors = (const float*)d_in[5];
  float* out = (float*)d_out;
  (void)d_ws; (void)ws_size;

  hipLaunchKernelGGL(render_all, dim3(NB*64), dim3(1024), 0, stream,
                     verts, faces, rot, pos, proj, colors, out);
}